// Round 1
// baseline (5713.877 us; speedup 1.0000x reference)
//
#include <hip/hip_runtime.h>
#include <cmath>

#define NVV 6000
#define NGG 3000
#define KSP 128
#define EDG 48000

static constexpr float SIGMA_INV = 1.0f / 2.5f;

// ---------------------------------------------------------------- rbf ------
__global__ __launch_bounds__(256) void rbf_k(const float* __restrict__ vert,
                                             const float* __restrict__ pos,
                                             float* __restrict__ rbf) {
  int g = blockIdx.x * 256 + threadIdx.x;
  int v = blockIdx.y;
  if (g >= NGG) return;
  float vx = vert[v * 3 + 0], vy = vert[v * 3 + 1], vz = vert[v * 3 + 2];
  float px = pos[g * 3 + 0], py = pos[g * 3 + 1], pz = pos[g * 3 + 2];
  float d2 = (vx * vx + vy * vy + vz * vz) + (px * px + py * py + pz * pz)
           - 2.0f * (vx * px + vy * py + vz * pz);
  float dist = sqrtf(fmaxf(d2, 0.0f));
  rbf[(size_t)v * NGG + g] = expf(-dist * SIGMA_INV);
}

// ------------------------------------------------- C = A(MxK) @ B(Kx64) ----
// grid.x = ceil(M/64), grid.y = #k-chunks (kchunk each). ATOMIC=1 -> +=.
template <int ATOMIC>
__global__ __launch_bounds__(256) void gemm_n64(const float* __restrict__ A,
                                                const float* __restrict__ B,
                                                float* __restrict__ C,
                                                int M, int K, int kchunk) {
  __shared__ float AsT[32][68];  // [k][row], stride 68 keeps b128 aligned, 2-way max
  __shared__ float Bs[32][64];
  const int m0 = blockIdx.x * 64;
  const int k0 = blockIdx.y * kchunk;
  const int kend = min(K, k0 + kchunk);
  const int t = threadIdx.x, tx = t & 15, ty = t >> 4;
  float acc[4][4] = {};
  for (int kb = k0; kb < kend; kb += 32) {
    const bool full = (m0 + 64 <= M) && (kb + 32 <= kend);
    if (full) {
#pragma unroll
      for (int i = 0; i < 2; ++i) {
        int l = (i * 256 + t) * 4;
        int r = l >> 5, c = l & 31;
        const float4 av = *(const float4*)(A + (size_t)(m0 + r) * K + kb + c);
        AsT[c + 0][r] = av.x; AsT[c + 1][r] = av.y;
        AsT[c + 2][r] = av.z; AsT[c + 3][r] = av.w;
        const float4 bv = *(const float4*)(B + (size_t)kb * 64 + l);
        *(float4*)(&Bs[0][0] + l) = bv;
      }
    } else {
#pragma unroll
      for (int i = 0; i < 8; ++i) {
        int l = i * 256 + t;
        int r = l >> 5, c = l & 31;
        AsT[c][r] = (m0 + r < M && kb + c < kend)
                        ? A[(size_t)(m0 + r) * K + kb + c] : 0.0f;
        int br = l >> 6, bc = l & 63;
        Bs[br][bc] = (kb + br < kend) ? B[(size_t)(kb + br) * 64 + bc] : 0.0f;
      }
    }
    __syncthreads();
#pragma unroll
    for (int kk = 0; kk < 32; ++kk) {
      float4 a4 = *(const float4*)&AsT[kk][ty * 4];
      float4 b4 = *(const float4*)&Bs[kk][tx * 4];
      float av[4] = {a4.x, a4.y, a4.z, a4.w};
      float bv[4] = {b4.x, b4.y, b4.z, b4.w};
#pragma unroll
      for (int ii = 0; ii < 4; ++ii)
#pragma unroll
        for (int jj = 0; jj < 4; ++jj)
          acc[ii][jj] = fmaf(av[ii], bv[jj], acc[ii][jj]);
    }
    __syncthreads();
  }
#pragma unroll
  for (int ii = 0; ii < 4; ++ii) {
    int gm = m0 + ty * 4 + ii;
    if (gm >= M) continue;
    if (ATOMIC) {
#pragma unroll
      for (int jj = 0; jj < 4; ++jj)
        atomicAdd(&C[(size_t)gm * 64 + tx * 4 + jj], acc[ii][jj]);
    } else {
      float4 o;
      o.x = acc[ii][0]; o.y = acc[ii][1]; o.z = acc[ii][2]; o.w = acc[ii][3];
      *(float4*)(C + (size_t)gm * 64 + tx * 4) = o;
    }
  }
}

// ------------------------------------ C(Mx64) += A^T @ B, A is [K x M] -----
// optional mass: B row v scaled by mass[v]. Always atomic (always k-split).
__global__ __launch_bounds__(256) void gemm_at_n64(const float* __restrict__ A,
                                                   const float* __restrict__ B,
                                                   const float* __restrict__ mass,
                                                   float* __restrict__ C,
                                                   int M, int K, int kchunk) {
  __shared__ float As[16][64];
  __shared__ float Bs[16][64];
  const int m0 = blockIdx.x * 64;
  const int k0 = blockIdx.y * kchunk;
  const int kend = min(K, k0 + kchunk);
  const int t = threadIdx.x, tx = t & 15, ty = t >> 4;
  float acc[4][4] = {};
  for (int kb = k0; kb < kend; kb += 16) {
#pragma unroll
    for (int i = 0; i < 4; ++i) {
      int l = i * 256 + t;
      int v = l >> 6, m = l & 63;
      int gv = kb + v;
      As[v][m] = (gv < kend && m0 + m < M) ? A[(size_t)gv * M + m0 + m] : 0.0f;
      float bval = 0.0f;
      if (gv < kend) {
        bval = B[(size_t)gv * 64 + m];
        if (mass) bval *= mass[gv];
      }
      Bs[v][m] = bval;
    }
    __syncthreads();
#pragma unroll
    for (int vv = 0; vv < 16; ++vv) {
      float4 a4 = *(const float4*)&As[vv][ty * 4];
      float4 b4 = *(const float4*)&Bs[vv][tx * 4];
      float av[4] = {a4.x, a4.y, a4.z, a4.w};
      float bv[4] = {b4.x, b4.y, b4.z, b4.w};
#pragma unroll
      for (int ii = 0; ii < 4; ++ii)
#pragma unroll
        for (int jj = 0; jj < 4; ++jj)
          acc[ii][jj] = fmaf(av[ii], bv[jj], acc[ii][jj]);
    }
    __syncthreads();
  }
#pragma unroll
  for (int ii = 0; ii < 4; ++ii) {
    int gm = m0 + ty * 4 + ii;
    if (gm < M) {
#pragma unroll
      for (int jj = 0; jj < 4; ++jj)
        atomicAdd(&C[(size_t)gm * 64 + tx * 4 + jj], acc[ii][jj]);
    }
  }
}

// ------------- out(Mx64) = concat(H1,H2,H3)(MxKin) @ W(64xKin)^T + b -------
// flags: relu. skip != null -> += skip. bias may be null.
__global__ __launch_bounds__(256) void lin_n64(const float* __restrict__ H1, int n1,
                                               const float* __restrict__ H2, int n2,
                                               const float* __restrict__ H3, int n3,
                                               const float* __restrict__ W,
                                               const float* __restrict__ bias,
                                               const float* __restrict__ skip,
                                               float* __restrict__ out,
                                               int M, int Kin, int relu) {
  __shared__ float HsT[32][68];  // [k][row]
  __shared__ float Ws[32][64];   // [k][outc]
  const int m0 = blockIdx.x * 64;
  const int t = threadIdx.x, tx = t & 15, ty = t >> 4;
  float acc[4][4] = {};
  for (int kb = 0; kb < Kin; kb += 32) {
#pragma unroll
    for (int i = 0; i < 8; ++i) {
      int l = i * 256 + t;
      int r = l >> 5, cg = l & 31;
      int kg = kb + cg, gm = m0 + r;
      float v = 0.0f;
      if (gm < M && kg < Kin) {
        if (kg < n1)            v = H1[(size_t)gm * n1 + kg];
        else if (kg < n1 + n2)  v = H2[(size_t)gm * n2 + (kg - n1)];
        else                    v = H3[(size_t)gm * n3 + (kg - n1 - n2)];
      }
      HsT[cg][r] = v;
      int kk = l >> 6, cc = l & 63;
      Ws[kk][cc] = (kb + kk < Kin) ? W[(size_t)cc * Kin + kb + kk] : 0.0f;
    }
    __syncthreads();
#pragma unroll
    for (int kk = 0; kk < 32; ++kk) {
      float4 a4 = *(const float4*)&HsT[kk][ty * 4];
      float4 b4 = *(const float4*)&Ws[kk][tx * 4];
      float av[4] = {a4.x, a4.y, a4.z, a4.w};
      float bv[4] = {b4.x, b4.y, b4.z, b4.w};
#pragma unroll
      for (int ii = 0; ii < 4; ++ii)
#pragma unroll
        for (int jj = 0; jj < 4; ++jj)
          acc[ii][jj] = fmaf(av[ii], bv[jj], acc[ii][jj]);
    }
    __syncthreads();
  }
#pragma unroll
  for (int ii = 0; ii < 4; ++ii) {
    int gm = m0 + ty * 4 + ii;
    if (gm >= M) continue;
#pragma unroll
    for (int jj = 0; jj < 4; ++jj) {
      int c = tx * 4 + jj;
      float v = acc[ii][jj];
      if (bias) v += bias[c];
      if (skip) v += skip[(size_t)gm * 64 + c];
      if (relu) v = fmaxf(v, 0.0f);
      out[(size_t)gm * 64 + c] = v;
    }
  }
}

// -------------------- gradient features: br/bi + tanh(gX*br + gY*bi) ------
__global__ __launch_bounds__(256) void gfeat_k(const float* __restrict__ gX,
                                               const float* __restrict__ gY,
                                               const float* __restrict__ Are,
                                               const float* __restrict__ Aim,
                                               float* __restrict__ gf) {
  __shared__ float areT[64][65];  // [k][c] = Are[c][k]
  __shared__ float aimT[64][65];
  const int t = threadIdx.x;
#pragma unroll
  for (int i = 0; i < 16; ++i) {
    int l = i * 256 + t;
    int cc = l >> 6, k = l & 63;
    areT[k][cc] = Are[cc * 64 + k];
    aimT[k][cc] = Aim[cc * 64 + k];
  }
  __syncthreads();
  const int c = t & 63, w = t >> 6;
  const int r0 = blockIdx.x * 64;
  for (int p = 0; p < 16; ++p) {
    int r = r0 + p * 4 + w;
    if (r < NVV) {
      const float* xr = gX + (size_t)r * 64;
      const float* yr = gY + (size_t)r * 64;
      float br = 0.0f, bi = 0.0f;
#pragma unroll 8
      for (int k = 0; k < 64; ++k) {
        float xv = xr[k], yv = yr[k];
        float ar = areT[k][c], ai = aimT[k][c];
        br += xv * ar - yv * ai;
        bi += yv * ar + xv * ai;
      }
      float xc = xr[c], yc = yr[c];
      gf[(size_t)r * 64 + c] = tanhf(xc * br + yc * bi);
    }
  }
}

// ------------------------------------------------------------- diffusion --
__global__ void sspec_k(const float* __restrict__ xs, const float* __restrict__ evals,
                        const float* __restrict__ tvec, float* __restrict__ S) {
  int idx = blockIdx.x * 256 + threadIdx.x;
  int k = idx >> 6, c = idx & 63;
  float tc = fmaxf(tvec[c], 1e-8f);
  S[idx] = expf(-evals[k] * tc) * xs[idx];
}

// ----------------------------------------------------------------- GCN ----
__global__ void count_k(const int* __restrict__ dst, int* __restrict__ cnt) {
  int e = blockIdx.x * 256 + threadIdx.x;
  if (e < EDG) atomicAdd(&cnt[dst[e]], 1);
}

__global__ void fill_k(const int* __restrict__ dst, const int* __restrict__ offs,
                       int* __restrict__ wcur, int* __restrict__ eidx) {
  int e = blockIdx.x * 256 + threadIdx.x;
  if (e < EDG) {
    int d = dst[e];
    int slot = atomicAdd(&wcur[d], 1);
    eidx[offs[d] + slot] = e;
  }
}

__global__ __launch_bounds__(1024) void scan_k(const int* __restrict__ cnt,
                                               int* __restrict__ offs,
                                               float* __restrict__ dinv) {
  __shared__ int buf[3072];
  __shared__ int ps[1024];
  const int t = threadIdx.x;
  for (int i = t; i < 3072; i += 1024) buf[i] = (i < NGG) ? cnt[i] : 0;
  __syncthreads();
  int b0 = buf[t * 3], b1 = buf[t * 3 + 1], b2 = buf[t * 3 + 2];
  ps[t] = b0 + b1 + b2;
  __syncthreads();
  for (int d = 1; d < 1024; d <<= 1) {
    int v = (t >= d) ? ps[t - d] : 0;
    __syncthreads();
    ps[t] += v;
    __syncthreads();
  }
  int base = (t > 0) ? ps[t - 1] : 0;
  if (t * 3     < NGG + 1) offs[t * 3]     = base;
  if (t * 3 + 1 < NGG + 1) offs[t * 3 + 1] = base + b0;
  if (t * 3 + 2 < NGG + 1) offs[t * 3 + 2] = base + b0 + b1;
  for (int i = t; i < NGG; i += 1024)
    dinv[i] = rsqrtf(1.0f + (float)cnt[i]);
}

__global__ void gcn_conv_k(const float* __restrict__ xw, const int* __restrict__ src,
                           const int* __restrict__ eidx, const int* __restrict__ offs,
                           const float* __restrict__ dinv, const float* __restrict__ bias,
                           float* __restrict__ out, int relu) {
  int g = blockIdx.x;
  int c = threadIdx.x;
  float dg = dinv[g];
  float acc = dg * dg * xw[(size_t)g * 64 + c];
  int j1 = offs[g + 1];
  for (int j = offs[g]; j < j1; ++j) {
    int e = eidx[j];
    int s = src[e];
    acc += dinv[s] * dg * xw[(size_t)s * 64 + c];
  }
  float v = acc + bias[c];
  if (relu) v = fmaxf(v, 0.0f);
  out[(size_t)g * 64 + c] = v;
}

// --------------------------------------------------------------- driver ---
extern "C" void kernel_launch(void* const* d_in, const int* in_sizes, int n_in,
                              void* d_out, int out_size, void* d_ws, size_t ws_size,
                              hipStream_t stream) {
  const float* surf_x   = (const float*)d_in[0];
  const float* graph_x  = (const float*)d_in[1];
  const float* vertices = (const float*)d_in[2];
  const float* pos      = (const float*)d_in[3];
  const float* mass     = (const float*)d_in[4];
  const float* evals    = (const float*)d_in[5];
  const float* evecs    = (const float*)d_in[6];
  const float* gradX    = (const float*)d_in[7];
  const float* gradY    = (const float*)d_in[8];
  const float* lin1_W   = (const float*)d_in[9];
  const float* lin1_b   = (const float*)d_in[10];
  const float* lin2_W   = (const float*)d_in[11];
  const float* lin2_b   = (const float*)d_in[12];
  const float* dtime    = (const float*)d_in[13];
  const float* A_re     = (const float*)d_in[14];
  const float* A_im     = (const float*)d_in[15];
  const float* mlpW0    = (const float*)d_in[16];
  const float* mlpb0    = (const float*)d_in[17];
  const float* mlpW1    = (const float*)d_in[18];
  const float* mlpb1    = (const float*)d_in[19];
  const float* mlpW2    = (const float*)d_in[20];
  const float* mlpb2    = (const float*)d_in[21];
  const float* gcnW1    = (const float*)d_in[22];
  const float* gcnb1    = (const float*)d_in[23];
  const float* gcnW2    = (const float*)d_in[24];
  const float* gcnb2    = (const float*)d_in[25];
  const float* mixW     = (const float*)d_in[26];
  const float* mixb     = (const float*)d_in[27];
  const int*   edges    = (const int*)d_in[28];
  const int* srcv = edges;
  const int* dstv = edges + EDG;
  (void)in_sizes; (void)n_in; (void)out_size; (void)ws_size;

  float* base = (float*)d_ws;
  size_t off = 0;
  auto alloc = [&](size_t n) {
    float* p = base + off;
    off += (n + 255) & ~(size_t)255;
    return p;
  };
  float* rbf   = alloc((size_t)NVV * NGG);  // 72 MB
  float* dxA   = alloc((size_t)NVV * 64);
  float* dxD   = alloc((size_t)NVV * 64);
  float* gxA   = alloc((size_t)NGG * 64);
  float* gxD   = alloc((size_t)NGG * 64);
  float* xspec = alloc((size_t)KSP * 64);
  float* Sbuf  = alloc((size_t)KSP * 64);
  float* xdiff = alloc((size_t)NVV * 64);
  float* gXb   = alloc((size_t)NVV * 64);
  float* gYb   = alloc((size_t)NVV * 64);
  float* gfeat = alloc((size_t)NVV * 64);
  float* h1    = alloc((size_t)NVV * 64);
  float* h2    = alloc((size_t)NVV * 64);
  float* xw    = alloc((size_t)NGG * 64);
  float* hg    = alloc((size_t)NGG * 64);
  float* dog   = alloc((size_t)NGG * 64);
  float* god   = alloc((size_t)NVV * 64);
  float* dinv  = alloc(NGG);
  int* cnt  = (int*)alloc(NGG);
  int* wcur = (int*)alloc(NGG);
  int* offs = (int*)alloc(NGG + 1);
  int* eidx = (int*)alloc(EDG);

  const int GBV = (NVV + 63) / 64;  // 94
  const int GBG = (NGG + 63) / 64;  // 47

  // rbf matrix (72 MB, reused across all iterations)
  rbf_k<<<dim3((NGG + 255) / 256, NVV), 256, 0, stream>>>(vertices, pos, rbf);

  // input linears
  lin_n64<<<GBV, 256, 0, stream>>>(surf_x, 5, nullptr, 0, nullptr, 0,
                                   lin1_W, lin1_b, nullptr, dxA, NVV, 5, 0);
  lin_n64<<<GBG, 256, 0, stream>>>(graph_x, 128, nullptr, 0, nullptr, 0,
                                   lin2_W, lin2_b, nullptr, gxA, NGG, 128, 0);

  // CSR build (per call; ws is re-poisoned every launch)
  hipMemsetAsync(cnt, 0, NGG * sizeof(int), stream);
  hipMemsetAsync(wcur, 0, NGG * sizeof(int), stream);
  count_k<<<(EDG + 255) / 256, 256, 0, stream>>>(dstv, cnt);
  scan_k<<<1, 1024, 0, stream>>>(cnt, offs, dinv);
  fill_k<<<(EDG + 255) / 256, 256, 0, stream>>>(dstv, offs, wcur, eidx);

  for (int i = 0; i < 4; ++i) {
    const float* W0  = mlpW0 + (size_t)i * 64 * 192;
    const float* b0  = mlpb0 + (size_t)i * 64;
    const float* W1  = mlpW1 + (size_t)i * 64 * 64;
    const float* b1  = mlpb1 + (size_t)i * 64;
    const float* W2  = mlpW2 + (size_t)i * 64 * 64;
    const float* b2  = mlpb2 + (size_t)i * 64;
    const float* WG1 = gcnW1 + (size_t)i * 64 * 64;
    const float* bG1 = gcnb1 + (size_t)i * 64;
    const float* WG2 = gcnW2 + (size_t)i * 64 * 64;
    const float* bG2 = gcnb2 + (size_t)i * 64;
    const float* Wm  = mixW + (size_t)i * 64 * 128;
    const float* bm  = mixb + (size_t)i * 64;

    // ---- diffusion block ----
    hipMemsetAsync(xspec, 0, (size_t)KSP * 64 * sizeof(float), stream);
    gemm_at_n64<<<dim3(2, 32), 256, 0, stream>>>(evecs, dxA, mass, xspec,
                                                 KSP, NVV, 188);
    sspec_k<<<(KSP * 64) / 256, 256, 0, stream>>>(xspec, evals, dtime + i * 64, Sbuf);
    gemm_n64<0><<<dim3(GBV, 1), 256, 0, stream>>>(evecs, Sbuf, xdiff, NVV, KSP, KSP);
    hipMemsetAsync(gXb, 0, (size_t)NVV * 64 * sizeof(float), stream);
    hipMemsetAsync(gYb, 0, (size_t)NVV * 64 * sizeof(float), stream);
    gemm_n64<1><<<dim3(GBV, 3), 256, 0, stream>>>(gradX, xdiff, gXb, NVV, NVV, 2000);
    gemm_n64<1><<<dim3(GBV, 3), 256, 0, stream>>>(gradY, xdiff, gYb, NVV, NVV, 2000);
    gfeat_k<<<GBV, 256, 0, stream>>>(gXb, gYb, A_re + (size_t)i * 4096,
                                     A_im + (size_t)i * 4096, gfeat);
    lin_n64<<<GBV, 256, 0, stream>>>(dxA, 64, xdiff, 64, gfeat, 64,
                                     W0, b0, nullptr, h1, NVV, 192, 1);
    lin_n64<<<GBV, 256, 0, stream>>>(h1, 64, nullptr, 0, nullptr, 0,
                                     W1, b1, nullptr, h2, NVV, 64, 1);
    lin_n64<<<GBV, 256, 0, stream>>>(h2, 64, nullptr, 0, nullptr, 0,
                                     W2, b2, dxA, dxD, NVV, 64, 0);

    // ---- GCN branch ----
    lin_n64<<<GBG, 256, 0, stream>>>(gxA, 64, nullptr, 0, nullptr, 0,
                                     WG1, nullptr, nullptr, xw, NGG, 64, 0);
    gcn_conv_k<<<NGG, 64, 0, stream>>>(xw, srcv, eidx, offs, dinv, bG1, hg, 1);
    lin_n64<<<GBG, 256, 0, stream>>>(hg, 64, nullptr, 0, nullptr, 0,
                                     WG2, nullptr, nullptr, xw, NGG, 64, 0);
    gcn_conv_k<<<NGG, 64, 0, stream>>>(xw, srcv, eidx, offs, dinv, bG2, gxD, 0);

    // ---- cross-domain exchange ----
    hipMemsetAsync(god, 0, (size_t)NVV * 64 * sizeof(float), stream);
    gemm_n64<1><<<dim3(GBV, 3), 256, 0, stream>>>(rbf, gxD, god, NVV, NGG, 1000);
    if (i < 3) {
      hipMemsetAsync(dog, 0, (size_t)NGG * 64 * sizeof(float), stream);
      gemm_at_n64<<<dim3(GBG, 6), 256, 0, stream>>>(rbf, dxD, nullptr, dog,
                                                    NGG, NVV, 1000);
    }
    float* dxOut = (i == 3) ? (float*)d_out : dxA;
    lin_n64<<<GBV, 256, 0, stream>>>(dxD, 64, god, 64, nullptr, 0,
                                     Wm, bm, nullptr, dxOut, NVV, 128, 0);
    if (i < 3)
      lin_n64<<<GBG, 256, 0, stream>>>(dog, 64, gxD, 64, nullptr, 0,
                                       Wm, bm, nullptr, gxA, NGG, 128, 0);
  }
}

// Round 2
// 2150.039 us; speedup vs baseline: 2.6576x; 2.6576x over previous
//
#include <hip/hip_runtime.h>
#include <cmath>

#define NVV 6000
#define NGG 3000
#define KSP 128
#define EDG 48000

static constexpr float SIGMA_INV = 1.0f / 2.5f;

typedef __attribute__((ext_vector_type(8))) short bfrag;
typedef __attribute__((ext_vector_type(4))) float f32x4;

__device__ inline ushort f2bf(float f) {
  unsigned u = __float_as_uint(f);
  return (ushort)((u + 0x7fffu + ((u >> 16) & 1u)) >> 16);
}
__device__ inline float bf2f(ushort h) { return __uint_as_float(((unsigned)h) << 16); }

__device__ inline bfrag bzero() {
  bfrag v;
#pragma unroll
  for (int i = 0; i < 8; ++i) v[i] = 0;
  return v;
}

struct bpair { bfrag hi, lo; };
__device__ inline bpair split8(const float* f) {
  union { ushort u[8]; bfrag v; } H, L;
#pragma unroll
  for (int i = 0; i < 8; ++i) {
    ushort h = f2bf(f[i]);
    H.u[i] = h;
    L.u[i] = f2bf(f[i] - bf2f(h));
  }
  return {H.v, L.v};
}

// =============================================================== rbf =======
// writes rbf[6000][3000] bf16 and rbfT[3000][6000] bf16
__global__ __launch_bounds__(256) void rbf_k(const float* __restrict__ vert,
                                             const float* __restrict__ pos,
                                             ushort* __restrict__ rbf,
                                             ushort* __restrict__ rbfT) {
  __shared__ float V[64][3], P[64][3];
  __shared__ ushort tile[64][72];
  const int v0 = blockIdx.x * 64, g0 = blockIdx.y * 64;
  const int t = threadIdx.x;
  if (t < 64) {
    int v = v0 + t;
    if (v < NVV) { V[t][0] = vert[v * 3]; V[t][1] = vert[v * 3 + 1]; V[t][2] = vert[v * 3 + 2]; }
    else { V[t][0] = V[t][1] = V[t][2] = 0.f; }
  } else if (t < 128) {
    int i = t - 64, g = g0 + i;
    if (g < NGG) { P[i][0] = pos[g * 3]; P[i][1] = pos[g * 3 + 1]; P[i][2] = pos[g * 3 + 2]; }
    else { P[i][0] = P[i][1] = P[i][2] = 0.f; }
  }
  __syncthreads();
#pragma unroll
  for (int rr = 0; rr < 4; ++rr) {
    int v = rr * 16 + (t >> 4);
    float vx = V[v][0], vy = V[v][1], vz = V[v][2];
    float vn = vx * vx + vy * vy + vz * vz;
#pragma unroll
    for (int i = 0; i < 4; ++i) {
      int g = (t & 15) * 4 + i;
      float px = P[g][0], py = P[g][1], pz = P[g][2];
      float d2 = vn + px * px + py * py + pz * pz - 2.0f * (vx * px + vy * py + vz * pz);
      float e = expf(-sqrtf(fmaxf(d2, 0.f)) * SIGMA_INV);
      tile[v][g] = f2bf(e);
    }
  }
  __syncthreads();
  {
    int v = t >> 2, u = (t & 3) * 16;
    int gv = v0 + v;
    if (gv < NVV) {
#pragma unroll
      for (int h = 0; h < 2; ++h) {
        int g = g0 + u + h * 8;
        if (g + 8 <= NGG)
          *(uint4*)(rbf + (size_t)gv * NGG + g) = *(const uint4*)&tile[v][u + h * 8];
      }
    }
  }
  {
    int g = t >> 2, u = (t & 3) * 16;
    int gg = g0 + g;
    if (gg < NGG) {
      ushort tmp[16];
#pragma unroll
      for (int h = 0; h < 16; ++h) tmp[h] = tile[u + h][g];
#pragma unroll
      for (int h = 0; h < 2; ++h) {
        int v = v0 + u + h * 8;
        if (v + 8 <= NVV)
          *(uint4*)(rbfT + (size_t)gg * NVV + v) = *(const uint4*)&tmp[h * 8];
      }
    }
  }
}

// ===================================================== big MFMA GEMM =======
// C(Mx64) (+)= A(MxK) @ B(Kx64).  B given as hi/lo transposed (BT[64][ldb]).
// AF32: A is f32 (split on the fly, 3-term product); else A bf16 single (2-term).
template <int AF32>
__global__ __launch_bounds__(256) void mfma_big(const void* __restrict__ A_, int lda,
                                                const ushort* __restrict__ Bh,
                                                const ushort* __restrict__ Bl, int ldb,
                                                float* __restrict__ C,
                                                int M, int K, int kchunk) {
  const int t = threadIdx.x, w = t >> 6, l = t & 63, la = l & 15, lb = l >> 4;
  const int m0 = blockIdx.x * 64;
  const int row = m0 + w * 16 + la;
  const bool rok = row < M;
  const int k0 = blockIdx.y * kchunk;
  const int kend = min(K, k0 + kchunk);
  f32x4 acc[4] = {{0.f,0.f,0.f,0.f},{0.f,0.f,0.f,0.f},{0.f,0.f,0.f,0.f},{0.f,0.f,0.f,0.f}};
  for (int kb = k0; kb < kend; kb += 32) {
    const int kk = kb + lb * 8;
    const bool kok = (kk + 8) <= kend;
    bfrag ah, al;
    if (AF32) {
      float fa[8];
      if (rok && kok) {
        const float* Ap = (const float*)A_ + (size_t)row * lda + kk;
        float4 v0 = *(const float4*)Ap;
        float4 v1 = *(const float4*)(Ap + 4);
        fa[0]=v0.x; fa[1]=v0.y; fa[2]=v0.z; fa[3]=v0.w;
        fa[4]=v1.x; fa[5]=v1.y; fa[6]=v1.z; fa[7]=v1.w;
      } else {
#pragma unroll
        for (int i = 0; i < 8; ++i) fa[i] = 0.f;
      }
      bpair a = split8(fa);
      ah = a.hi; al = a.lo;
    } else {
      ah = (rok && kok) ? *(const bfrag*)((const ushort*)A_ + (size_t)row * lda + kk)
                        : bzero();
      al = bzero();
    }
#pragma unroll
    for (int j = 0; j < 4; ++j) {
      bfrag bh, bl;
      if (kok) {
        bh = *(const bfrag*)(Bh + (size_t)(j * 16 + la) * ldb + kk);
        bl = *(const bfrag*)(Bl + (size_t)(j * 16 + la) * ldb + kk);
      } else { bh = bzero(); bl = bzero(); }
      acc[j] = __builtin_amdgcn_mfma_f32_16x16x32_bf16(ah, bh, acc[j], 0, 0, 0);
      acc[j] = __builtin_amdgcn_mfma_f32_16x16x32_bf16(ah, bl, acc[j], 0, 0, 0);
      if (AF32)
        acc[j] = __builtin_amdgcn_mfma_f32_16x16x32_bf16(al, bh, acc[j], 0, 0, 0);
    }
  }
  const int orow = m0 + w * 16 + lb * 4;
  if (gridDim.y == 1) {
#pragma unroll
    for (int j = 0; j < 4; ++j)
#pragma unroll
      for (int r = 0; r < 4; ++r)
        if (orow + r < M) C[(size_t)(orow + r) * 64 + j * 16 + la] = acc[j][r];
  } else {
#pragma unroll
    for (int j = 0; j < 4; ++j)
#pragma unroll
      for (int r = 0; r < 4; ++r)
        if (orow + r < M) atomicAdd(&C[(size_t)(orow + r) * 64 + j * 16 + la], acc[j][r]);
  }
}

// ================================================== generic MFMA linear ====
// out(Mx64) = concat(H1,H2,H3) @ W^T [+bias][+skip][relu], W as BT hi/lo [64][Kin]
__global__ __launch_bounds__(256) void mfma_lin(
    const float* __restrict__ H1, int n1, const float* __restrict__ H2, int n2,
    const float* __restrict__ H3, int n3,
    const ushort* __restrict__ Wh, const ushort* __restrict__ Wl,
    const float* __restrict__ bias, const float* __restrict__ skip,
    float* __restrict__ out, int M, int Kin, int relu) {
  const int t = threadIdx.x, w = t >> 6, l = t & 63, la = l & 15, lb = l >> 4;
  const int m0 = blockIdx.x * 64;
  const int row = m0 + w * 16 + la;
  const bool rok = row < M;
  f32x4 acc[4] = {{0.f,0.f,0.f,0.f},{0.f,0.f,0.f,0.f},{0.f,0.f,0.f,0.f},{0.f,0.f,0.f,0.f}};
  for (int kb = 0; kb < Kin; kb += 32) {
    const float* src; int ldx, kl;
    if (kb < n1)            { src = H1; ldx = n1; kl = kb; }
    else if (kb < n1 + n2)  { src = H2; ldx = n2; kl = kb - n1; }
    else                    { src = H3; ldx = n3; kl = kb - n1 - n2; }
    const bool full = (kb + 32) <= Kin;
    float fa[8];
    if (rok && full) {
      const float* p = src + (size_t)row * ldx + kl + lb * 8;
      float4 v0 = *(const float4*)p;
      float4 v1 = *(const float4*)(p + 4);
      fa[0]=v0.x; fa[1]=v0.y; fa[2]=v0.z; fa[3]=v0.w;
      fa[4]=v1.x; fa[5]=v1.y; fa[6]=v1.z; fa[7]=v1.w;
    } else {
#pragma unroll
      for (int i = 0; i < 8; ++i) {
        int kg = kb + lb * 8 + i;
        fa[i] = (rok && kg < Kin) ? src[(size_t)row * ldx + kl + lb * 8 + i] : 0.f;
      }
    }
    bpair a = split8(fa);
#pragma unroll
    for (int j = 0; j < 4; ++j) {
      bfrag wh, wl;
      if (full) {
        wh = *(const bfrag*)(Wh + (size_t)(j * 16 + la) * Kin + kb + lb * 8);
        wl = *(const bfrag*)(Wl + (size_t)(j * 16 + la) * Kin + kb + lb * 8);
      } else {
        union { ushort u[8]; bfrag v; } th, tl;
#pragma unroll
        for (int i = 0; i < 8; ++i) {
          int kg = kb + lb * 8 + i;
          th.u[i] = (kg < Kin) ? Wh[(size_t)(j * 16 + la) * Kin + kg] : 0;
          tl.u[i] = (kg < Kin) ? Wl[(size_t)(j * 16 + la) * Kin + kg] : 0;
        }
        wh = th.v; wl = tl.v;
      }
      acc[j] = __builtin_amdgcn_mfma_f32_16x16x32_bf16(a.hi, wh, acc[j], 0, 0, 0);
      acc[j] = __builtin_amdgcn_mfma_f32_16x16x32_bf16(a.hi, wl, acc[j], 0, 0, 0);
      acc[j] = __builtin_amdgcn_mfma_f32_16x16x32_bf16(a.lo, wh, acc[j], 0, 0, 0);
    }
  }
  const int orow = m0 + w * 16 + lb * 4;
#pragma unroll
  for (int j = 0; j < 4; ++j) {
    int col = j * 16 + la;
#pragma unroll
    for (int r = 0; r < 4; ++r) {
      int gr = orow + r;
      if (gr < M) {
        float v = acc[j][r];
        if (bias) v += bias[col];
        if (skip) v += skip[(size_t)gr * 64 + col];
        if (relu) v = fmaxf(v, 0.f);
        out[(size_t)gr * 64 + col] = v;
      }
    }
  }
}

// ======================================================== fused MLP ========
// h1=relu(cat(x,xd,gf)@W0^T+b0); h2=relu(h1@W1^T+b1); out=h2@W2^T+b2+x
__global__ __launch_bounds__(256) void mlp_fused(
    const float* __restrict__ x, const float* __restrict__ xd, const float* __restrict__ gf,
    const ushort* __restrict__ W0h, const ushort* __restrict__ W0l, const float* __restrict__ b0,
    const ushort* __restrict__ W1h, const ushort* __restrict__ W1l, const float* __restrict__ b1,
    const ushort* __restrict__ W2h, const ushort* __restrict__ W2l, const float* __restrict__ b2,
    float* __restrict__ out, int M) {
  __shared__ ushort Hh[64][72], Hl[64][72];
  const int t = threadIdx.x, w = t >> 6, l = t & 63, la = l & 15, lb = l >> 4;
  const int m0 = blockIdx.x * 64;
  const int row = m0 + w * 16 + la;
  const bool rok = row < M;
  f32x4 acc[4] = {{0.f,0.f,0.f,0.f},{0.f,0.f,0.f,0.f},{0.f,0.f,0.f,0.f},{0.f,0.f,0.f,0.f}};
  for (int kb = 0; kb < 192; kb += 32) {
    const float* src = kb < 64 ? x : (kb < 128 ? xd : gf);
    int kl = kb & 63;
    float fa[8];
    if (rok) {
      const float* p = src + (size_t)row * 64 + kl + lb * 8;
      float4 v0 = *(const float4*)p;
      float4 v1 = *(const float4*)(p + 4);
      fa[0]=v0.x; fa[1]=v0.y; fa[2]=v0.z; fa[3]=v0.w;
      fa[4]=v1.x; fa[5]=v1.y; fa[6]=v1.z; fa[7]=v1.w;
    } else {
#pragma unroll
      for (int i = 0; i < 8; ++i) fa[i] = 0.f;
    }
    bpair a = split8(fa);
#pragma unroll
    for (int j = 0; j < 4; ++j) {
      bfrag wh = *(const bfrag*)(W0h + (size_t)(j * 16 + la) * 192 + kb + lb * 8);
      bfrag wl = *(const bfrag*)(W0l + (size_t)(j * 16 + la) * 192 + kb + lb * 8);
      acc[j] = __builtin_amdgcn_mfma_f32_16x16x32_bf16(a.hi, wh, acc[j], 0, 0, 0);
      acc[j] = __builtin_amdgcn_mfma_f32_16x16x32_bf16(a.hi, wl, acc[j], 0, 0, 0);
      acc[j] = __builtin_amdgcn_mfma_f32_16x16x32_bf16(a.lo, wh, acc[j], 0, 0, 0);
    }
  }
#pragma unroll
  for (int j = 0; j < 4; ++j)
#pragma unroll
    for (int r = 0; r < 4; ++r) {
      float v = fmaxf(acc[j][r] + b0[j * 16 + la], 0.f);
      ushort h = f2bf(v);
      Hh[w * 16 + lb * 4 + r][j * 16 + la] = h;
      Hl[w * 16 + lb * 4 + r][j * 16 + la] = f2bf(v - bf2f(h));
    }
  __syncthreads();
  f32x4 acc2[4] = {{0.f,0.f,0.f,0.f},{0.f,0.f,0.f,0.f},{0.f,0.f,0.f,0.f},{0.f,0.f,0.f,0.f}};
#pragma unroll
  for (int kb = 0; kb < 64; kb += 32) {
    bfrag ah = *(const bfrag*)&Hh[w * 16 + la][kb + lb * 8];
    bfrag al = *(const bfrag*)&Hl[w * 16 + la][kb + lb * 8];
#pragma unroll
    for (int j = 0; j < 4; ++j) {
      bfrag wh = *(const bfrag*)(W1h + (size_t)(j * 16 + la) * 64 + kb + lb * 8);
      bfrag wl = *(const bfrag*)(W1l + (size_t)(j * 16 + la) * 64 + kb + lb * 8);
      acc2[j] = __builtin_amdgcn_mfma_f32_16x16x32_bf16(ah, wh, acc2[j], 0, 0, 0);
      acc2[j] = __builtin_amdgcn_mfma_f32_16x16x32_bf16(ah, wl, acc2[j], 0, 0, 0);
      acc2[j] = __builtin_amdgcn_mfma_f32_16x16x32_bf16(al, wh, acc2[j], 0, 0, 0);
    }
  }
  __syncthreads();
#pragma unroll
  for (int j = 0; j < 4; ++j)
#pragma unroll
    for (int r = 0; r < 4; ++r) {
      float v = fmaxf(acc2[j][r] + b1[j * 16 + la], 0.f);
      ushort h = f2bf(v);
      Hh[w * 16 + lb * 4 + r][j * 16 + la] = h;
      Hl[w * 16 + lb * 4 + r][j * 16 + la] = f2bf(v - bf2f(h));
    }
  __syncthreads();
  f32x4 acc3[4] = {{0.f,0.f,0.f,0.f},{0.f,0.f,0.f,0.f},{0.f,0.f,0.f,0.f},{0.f,0.f,0.f,0.f}};
#pragma unroll
  for (int kb = 0; kb < 64; kb += 32) {
    bfrag ah = *(const bfrag*)&Hh[w * 16 + la][kb + lb * 8];
    bfrag al = *(const bfrag*)&Hl[w * 16 + la][kb + lb * 8];
#pragma unroll
    for (int j = 0; j < 4; ++j) {
      bfrag wh = *(const bfrag*)(W2h + (size_t)(j * 16 + la) * 64 + kb + lb * 8);
      bfrag wl = *(const bfrag*)(W2l + (size_t)(j * 16 + la) * 64 + kb + lb * 8);
      acc3[j] = __builtin_amdgcn_mfma_f32_16x16x32_bf16(ah, wh, acc3[j], 0, 0, 0);
      acc3[j] = __builtin_amdgcn_mfma_f32_16x16x32_bf16(ah, wl, acc3[j], 0, 0, 0);
      acc3[j] = __builtin_amdgcn_mfma_f32_16x16x32_bf16(al, wh, acc3[j], 0, 0, 0);
    }
  }
  const int orow = m0 + w * 16 + lb * 4;
#pragma unroll
  for (int j = 0; j < 4; ++j) {
    int col = j * 16 + la;
#pragma unroll
    for (int r = 0; r < 4; ++r) {
      int gr = orow + r;
      if (gr < M)
        out[(size_t)gr * 64 + col] = acc3[j][r] + b2[col] + x[(size_t)gr * 64 + col];
    }
  }
}

// ================================================ transpose (+split) =======
// BT[col0+c][m] = bf16split( X[m][col0+c] * scale[m] ), m in [m0, m0+64)
__global__ __launch_bounds__(256) void t64_k(const float* __restrict__ X, int ldx, int col0,
                                             int rows, const float* __restrict__ scale,
                                             ushort* __restrict__ Bh, ushort* __restrict__ Bl,
                                             int ldb) {
  __shared__ ushort Th[64][72], Tl[64][72];
  const int m0 = blockIdx.x * 64, t = threadIdx.x;
  const int r = t >> 4, c4 = (t & 15) * 4;
  for (int rr = 0; rr < 64; rr += 16) {
    int m = m0 + rr + r;
    float4 v = {0.f, 0.f, 0.f, 0.f};
    float s = 1.f;
    if (m < rows) {
      v = *(const float4*)(X + (size_t)m * ldx + col0 + c4);
      if (scale) s = scale[m];
    }
    float fv[4] = {v.x * s, v.y * s, v.z * s, v.w * s};
#pragma unroll
    for (int i = 0; i < 4; ++i) {
      ushort h = f2bf(fv[i]);
      Th[c4 + i][rr + r] = h;
      Tl[c4 + i][rr + r] = f2bf(fv[i] - bf2f(h));
    }
  }
  __syncthreads();
  const int c = t >> 2, u = (t & 3) * 16;
#pragma unroll
  for (int h = 0; h < 2; ++h) {
    *(uint4*)(Bh + (size_t)(col0 + c) * ldb + m0 + u + h * 8) = *(const uint4*)&Th[c][u + h * 8];
    *(uint4*)(Bl + (size_t)(col0 + c) * ldb + m0 + u + h * 8) = *(const uint4*)&Tl[c][u + h * 8];
  }
}

// f32 transpose (for evecsT)
__global__ __launch_bounds__(256) void t64f_k(const float* __restrict__ X, int ldx, int col0,
                                              int rows, float* __restrict__ BT, int ldb) {
  __shared__ float T[64][68];
  const int m0 = blockIdx.x * 64, t = threadIdx.x;
  const int r = t >> 4, c4 = (t & 15) * 4;
  for (int rr = 0; rr < 64; rr += 16) {
    int m = m0 + rr + r;
    float4 v = {0.f, 0.f, 0.f, 0.f};
    if (m < rows) v = *(const float4*)(X + (size_t)m * ldx + col0 + c4);
    T[c4 + 0][rr + r] = v.x; T[c4 + 1][rr + r] = v.y;
    T[c4 + 2][rr + r] = v.z; T[c4 + 3][rr + r] = v.w;
  }
  __syncthreads();
  const int c = t >> 2, u = (t & 3) * 16;
#pragma unroll
  for (int h = 0; h < 4; ++h)
    *(float4*)(BT + (size_t)(col0 + c) * ldb + m0 + u + h * 4) = *(const float4*)&T[c][u + h * 4];
}

// ====================================================== small kernels ======
__global__ void wsplit_k(const float* __restrict__ src, ushort* __restrict__ hi,
                         ushort* __restrict__ lo, int n) {
  int i = blockIdx.x * 256 + threadIdx.x;
  if (i < n) {
    float f = src[i];
    ushort h = f2bf(f);
    hi[i] = h;
    lo[i] = f2bf(f - bf2f(h));
  }
}

// build Wbr=[Are|-Aim], Wbi=[Aim|Are] (hi/lo) for all 4 batches; idx over 4*64*64
__global__ void buildAW_k(const float* __restrict__ Are, const float* __restrict__ Aim,
                          ushort* __restrict__ brh, ushort* __restrict__ brl,
                          ushort* __restrict__ bih, ushort* __restrict__ bil) {
  int idx = blockIdx.x * 256 + threadIdx.x;
  if (idx >= 4 * 64 * 64) return;
  int b = idx >> 12, c = (idx >> 6) & 63, k = idx & 63;
  float ar = Are[idx], ai = Aim[idx];
  size_t base = (size_t)b * 64 * 128 + (size_t)c * 128;
  ushort h;
  h = f2bf(ar);  brh[base + k] = h;        brl[base + k] = f2bf(ar - bf2f(h));
  h = f2bf(-ai); brh[base + 64 + k] = h;   brl[base + 64 + k] = f2bf(-ai - bf2f(h));
  h = f2bf(ai);  bih[base + k] = h;        bil[base + k] = f2bf(ai - bf2f(h));
  h = f2bf(ar);  bih[base + 64 + k] = h;   bil[base + 64 + k] = f2bf(ar - bf2f(h));
}

__global__ void sspec_k(const float* __restrict__ xs, const float* __restrict__ evals,
                        const float* __restrict__ tvec, ushort* __restrict__ Sh,
                        ushort* __restrict__ Sl) {
  int idx = blockIdx.x * 256 + threadIdx.x;  // KSP*64
  int k = idx >> 6, c = idx & 63;
  float tc = fmaxf(tvec[c], 1e-8f);
  float f = expf(-evals[k] * tc) * xs[idx];
  ushort h = f2bf(f);
  Sh[c * KSP + k] = h;
  Sl[c * KSP + k] = f2bf(f - bf2f(h));
}

__global__ void gcomb_k(const float* __restrict__ gX, const float* __restrict__ gY,
                        const float* __restrict__ br, const float* __restrict__ bi,
                        float* __restrict__ gf, int n) {
  int i = blockIdx.x * 256 + threadIdx.x;
  if (i < n) gf[i] = tanhf(gX[i] * br[i] + gY[i] * bi[i]);
}

// ----------------------------------------------------------------- GCN ----
__global__ void count_k(const int* __restrict__ dst, int* __restrict__ cnt) {
  int e = blockIdx.x * 256 + threadIdx.x;
  if (e < EDG) atomicAdd(&cnt[dst[e]], 1);
}

__global__ void fill_k(const int* __restrict__ dst, const int* __restrict__ offs,
                       int* __restrict__ wcur, int* __restrict__ eidx) {
  int e = blockIdx.x * 256 + threadIdx.x;
  if (e < EDG) {
    int d = dst[e];
    int slot = atomicAdd(&wcur[d], 1);
    eidx[offs[d] + slot] = e;
  }
}

__global__ __launch_bounds__(1024) void scan_k(const int* __restrict__ cnt,
                                               int* __restrict__ offs,
                                               float* __restrict__ dinv) {
  __shared__ int buf[3072];
  __shared__ int ps[1024];
  const int t = threadIdx.x;
  for (int i = t; i < 3072; i += 1024) buf[i] = (i < NGG) ? cnt[i] : 0;
  __syncthreads();
  int b0 = buf[t * 3], b1 = buf[t * 3 + 1], b2 = buf[t * 3 + 2];
  ps[t] = b0 + b1 + b2;
  __syncthreads();
  for (int d = 1; d < 1024; d <<= 1) {
    int v = (t >= d) ? ps[t - d] : 0;
    __syncthreads();
    ps[t] += v;
    __syncthreads();
  }
  int base = (t > 0) ? ps[t - 1] : 0;
  if (t * 3 < NGG + 1) offs[t * 3] = base;
  if (t * 3 + 1 < NGG + 1) offs[t * 3 + 1] = base + b0;
  if (t * 3 + 2 < NGG + 1) offs[t * 3 + 2] = base + b0 + b1;
  for (int i = t; i < NGG; i += 1024) dinv[i] = rsqrtf(1.0f + (float)cnt[i]);
}

__global__ __launch_bounds__(64) void gcn_conv_k(const float* __restrict__ xw,
                                                 const int* __restrict__ src,
                                                 const int* __restrict__ eidx,
                                                 const int* __restrict__ offs,
                                                 const float* __restrict__ dinv,
                                                 const float* __restrict__ bias,
                                                 float* __restrict__ out, int relu) {
  int g = blockIdx.x;
  int c = threadIdx.x;
  float dg = dinv[g];
  float acc = dg * dg * xw[(size_t)g * 64 + c];
  int j1 = offs[g + 1];
  for (int j = offs[g]; j < j1; ++j) {
    int s = src[eidx[j]];
    acc += dinv[s] * dg * xw[(size_t)s * 64 + c];
  }
  float v = acc + bias[c];
  if (relu) v = fmaxf(v, 0.f);
  out[(size_t)g * 64 + c] = v;
}

// =============================================================== driver ====
extern "C" void kernel_launch(void* const* d_in, const int* in_sizes, int n_in,
                              void* d_out, int out_size, void* d_ws, size_t ws_size,
                              hipStream_t stream) {
  const float* surf_x   = (const float*)d_in[0];
  const float* graph_x  = (const float*)d_in[1];
  const float* vertices = (const float*)d_in[2];
  const float* pos      = (const float*)d_in[3];
  const float* mass     = (const float*)d_in[4];
  const float* evals    = (const float*)d_in[5];
  const float* evecs    = (const float*)d_in[6];
  const float* gradX    = (const float*)d_in[7];
  const float* gradY    = (const float*)d_in[8];
  const float* lin1_W   = (const float*)d_in[9];
  const float* lin1_b   = (const float*)d_in[10];
  const float* lin2_W   = (const float*)d_in[11];
  const float* lin2_b   = (const float*)d_in[12];
  const float* dtime    = (const float*)d_in[13];
  const float* A_re     = (const float*)d_in[14];
  const float* A_im     = (const float*)d_in[15];
  const float* mlpW0    = (const float*)d_in[16];
  const float* mlpb0    = (const float*)d_in[17];
  const float* mlpW1    = (const float*)d_in[18];
  const float* mlpb1    = (const float*)d_in[19];
  const float* mlpW2    = (const float*)d_in[20];
  const float* mlpb2    = (const float*)d_in[21];
  const float* gcnW1    = (const float*)d_in[22];
  const float* gcnb1    = (const float*)d_in[23];
  const float* gcnW2    = (const float*)d_in[24];
  const float* gcnb2    = (const float*)d_in[25];
  const float* mixW     = (const float*)d_in[26];
  const float* mixb     = (const float*)d_in[27];
  const int*   edges    = (const int*)d_in[28];
  const int* srcv = edges;
  const int* dstv = edges + EDG;
  (void)in_sizes; (void)n_in; (void)out_size; (void)ws_size;

  char* base = (char*)d_ws;
  size_t off = 0;
  auto allocB = [&](size_t bytes) {
    char* p = base + off;
    off = (off + bytes + 1023) & ~(size_t)1023;
    return p;
  };
  // big bf16 matrices
  ushort* rbf    = (ushort*)allocB((size_t)NVV * NGG * 2);   // 36 MB
  ushort* rbfT   = (ushort*)allocB((size_t)NGG * NVV * 2);   // 36 MB
  float*  evecsT = (float*)allocB((size_t)KSP * 6016 * 4);   // 3 MB
  // BT hi/lo buffers
  ushort* btMh = (ushort*)allocB((size_t)64 * 6016 * 2);
  ushort* btMl = (ushort*)allocB((size_t)64 * 6016 * 2);
  ushort* btXh = (ushort*)allocB((size_t)64 * 6016 * 2);
  ushort* btXl = (ushort*)allocB((size_t)64 * 6016 * 2);
  ushort* btDh = (ushort*)allocB((size_t)64 * 6016 * 2);
  ushort* btDl = (ushort*)allocB((size_t)64 * 6016 * 2);
  ushort* btGh = (ushort*)allocB((size_t)64 * 3008 * 2);
  ushort* btGl = (ushort*)allocB((size_t)64 * 3008 * 2);
  ushort* Sh   = (ushort*)allocB((size_t)64 * KSP * 2);
  ushort* Sl   = (ushort*)allocB((size_t)64 * KSP * 2);
  // weight hi/lo
  ushort* w0h = (ushort*)allocB((size_t)4 * 64 * 192 * 2);
  ushort* w0l = (ushort*)allocB((size_t)4 * 64 * 192 * 2);
  ushort* w1h = (ushort*)allocB((size_t)4 * 4096 * 2);
  ushort* w1l = (ushort*)allocB((size_t)4 * 4096 * 2);
  ushort* w2h = (ushort*)allocB((size_t)4 * 4096 * 2);
  ushort* w2l = (ushort*)allocB((size_t)4 * 4096 * 2);
  ushort* wg1h = (ushort*)allocB((size_t)4 * 4096 * 2);
  ushort* wg1l = (ushort*)allocB((size_t)4 * 4096 * 2);
  ushort* wg2h = (ushort*)allocB((size_t)4 * 4096 * 2);
  ushort* wg2l = (ushort*)allocB((size_t)4 * 4096 * 2);
  ushort* wmh = (ushort*)allocB((size_t)4 * 64 * 128 * 2);
  ushort* wml = (ushort*)allocB((size_t)4 * 64 * 128 * 2);
  ushort* wl1h = (ushort*)allocB((size_t)64 * 5 * 2 + 16);
  ushort* wl1l = (ushort*)allocB((size_t)64 * 5 * 2 + 16);
  ushort* wl2h = (ushort*)allocB((size_t)64 * 128 * 2);
  ushort* wl2l = (ushort*)allocB((size_t)64 * 128 * 2);
  ushort* wbrh = (ushort*)allocB((size_t)4 * 64 * 128 * 2);
  ushort* wbrl = (ushort*)allocB((size_t)4 * 64 * 128 * 2);
  ushort* wbih = (ushort*)allocB((size_t)4 * 64 * 128 * 2);
  ushort* wbil = (ushort*)allocB((size_t)4 * 64 * 128 * 2);
  // f32 activations
  float* dxA   = (float*)allocB((size_t)NVV * 64 * 4);
  float* dxD   = (float*)allocB((size_t)NVV * 64 * 4);
  float* xdiff = (float*)allocB((size_t)NVV * 64 * 4);
  float* gXb   = (float*)allocB((size_t)NVV * 64 * 4);
  float* gYb   = (float*)allocB((size_t)NVV * 64 * 4);
  float* gfeat = (float*)allocB((size_t)NVV * 64 * 4);
  float* god   = (float*)allocB((size_t)NVV * 64 * 4);
  float* brb   = (float*)allocB((size_t)NVV * 64 * 4);
  float* bib   = (float*)allocB((size_t)NVV * 64 * 4);
  float* gxA   = (float*)allocB((size_t)NGG * 64 * 4);
  float* gxD   = (float*)allocB((size_t)NGG * 64 * 4);
  float* xw    = (float*)allocB((size_t)NGG * 64 * 4);
  float* hg    = (float*)allocB((size_t)NGG * 64 * 4);
  float* dog   = (float*)allocB((size_t)NGG * 64 * 4);
  float* xspec = (float*)allocB((size_t)KSP * 64 * 4);
  float* dinv  = (float*)allocB(NGG * 4);
  int* cnt  = (int*)allocB(NGG * 4);
  int* wcur = (int*)allocB(NGG * 4);
  int* offs = (int*)allocB((NGG + 1) * 4);
  int* eidx = (int*)allocB(EDG * 4);

  const int GBV = (NVV + 63) / 64;  // 94
  const int GBG = (NGG + 63) / 64;  // 47

  // ---- setup (once per launch) ----
  rbf_k<<<dim3(GBV, GBG), 256, 0, stream>>>(vertices, pos, rbf, rbfT);
  wsplit_k<<<(4*64*192+255)/256, 256, 0, stream>>>(mlpW0, w0h, w0l, 4*64*192);
  wsplit_k<<<(4*4096+255)/256, 256, 0, stream>>>(mlpW1, w1h, w1l, 4*4096);
  wsplit_k<<<(4*4096+255)/256, 256, 0, stream>>>(mlpW2, w2h, w2l, 4*4096);
  wsplit_k<<<(4*4096+255)/256, 256, 0, stream>>>(gcnW1, wg1h, wg1l, 4*4096);
  wsplit_k<<<(4*4096+255)/256, 256, 0, stream>>>(gcnW2, wg2h, wg2l, 4*4096);
  wsplit_k<<<(4*64*128+255)/256, 256, 0, stream>>>(mixW, wmh, wml, 4*64*128);
  wsplit_k<<<2, 256, 0, stream>>>(lin1_W, wl1h, wl1l, 64*5);
  wsplit_k<<<32, 256, 0, stream>>>(lin2_W, wl2h, wl2l, 64*128);
  buildAW_k<<<64, 256, 0, stream>>>(A_re, A_im, wbrh, wbrl, wbih, wbil);
  t64f_k<<<GBV, 256, 0, stream>>>(evecs, KSP, 0, NVV, evecsT, 6016);
  t64f_k<<<GBV, 256, 0, stream>>>(evecs, KSP, 64, NVV, evecsT, 6016);

  // CSR
  hipMemsetAsync(cnt, 0, NGG * sizeof(int), stream);
  hipMemsetAsync(wcur, 0, NGG * sizeof(int), stream);
  count_k<<<(EDG + 255) / 256, 256, 0, stream>>>(dstv, cnt);
  scan_k<<<1, 1024, 0, stream>>>(cnt, offs, dinv);
  fill_k<<<(EDG + 255) / 256, 256, 0, stream>>>(dstv, offs, wcur, eidx);

  // input linears
  mfma_lin<<<GBV, 256, 0, stream>>>(surf_x, 5, nullptr, 0, nullptr, 0,
                                    wl1h, wl1l, lin1_b, nullptr, dxA, NVV, 5, 0);
  mfma_lin<<<GBG, 256, 0, stream>>>(graph_x, 128, nullptr, 0, nullptr, 0,
                                    wl2h, wl2l, lin2_b, nullptr, gxA, NGG, 128, 0);

  for (int i = 0; i < 4; ++i) {
    const float* b0 = mlpb0 + (size_t)i * 64;
    const float* b1 = mlpb1 + (size_t)i * 64;
    const float* b2 = mlpb2 + (size_t)i * 64;
    const float* bG1 = gcnb1 + (size_t)i * 64;
    const float* bG2 = gcnb2 + (size_t)i * 64;
    const float* bm = mixb + (size_t)i * 64;

    // ---- diffusion: spectral ----
    t64_k<<<GBV, 256, 0, stream>>>(dxA, 64, 0, NVV, mass, btMh, btMl, 6016);
    hipMemsetAsync(xspec, 0, (size_t)KSP * 64 * 4, stream);
    mfma_big<1><<<dim3(2, 47), 256, 0, stream>>>(evecsT, 6016, btMh, btMl, 6016,
                                                 xspec, KSP, NVV, 128);
    sspec_k<<<(KSP * 64) / 256, 256, 0, stream>>>(xspec, evals, dtime + i * 64, Sh, Sl);
    mfma_big<1><<<dim3(GBV, 1), 256, 0, stream>>>(evecs, KSP, Sh, Sl, KSP,
                                                  xdiff, NVV, KSP, KSP);
    // ---- gradients ----
    t64_k<<<GBV, 256, 0, stream>>>(xdiff, 64, 0, NVV, nullptr, btXh, btXl, 6016);
    hipMemsetAsync(gXb, 0, (size_t)NVV * 64 * 4, stream);
    hipMemsetAsync(gYb, 0, (size_t)NVV * 64 * 4, stream);
    mfma_big<1><<<dim3(GBV, 12), 256, 0, stream>>>(gradX, NVV, btXh, btXl, 6016,
                                                   gXb, NVV, NVV, 512);
    mfma_big<1><<<dim3(GBV, 12), 256, 0, stream>>>(gradY, NVV, btXh, btXl, 6016,
                                                   gYb, NVV, NVV, 512);
    // gfeat = tanh(gX*br + gY*bi)
    mfma_lin<<<GBV, 256, 0, stream>>>(gXb, 64, gYb, 64, nullptr, 0,
                                      wbrh + (size_t)i * 8192, wbrl + (size_t)i * 8192,
                                      nullptr, nullptr, brb, NVV, 128, 0);
    mfma_lin<<<GBV, 256, 0, stream>>>(gXb, 64, gYb, 64, nullptr, 0,
                                      wbih + (size_t)i * 8192, wbil + (size_t)i * 8192,
                                      nullptr, nullptr, bib, NVV, 128, 0);
    gcomb_k<<<(NVV * 64 + 255) / 256, 256, 0, stream>>>(gXb, gYb, brb, bib, gfeat, NVV * 64);
    // MLP + skip
    mlp_fused<<<GBV, 256, 0, stream>>>(dxA, xdiff, gfeat,
                                       w0h + (size_t)i * 12288, w0l + (size_t)i * 12288, b0,
                                       w1h + (size_t)i * 4096, w1l + (size_t)i * 4096, b1,
                                       w2h + (size_t)i * 4096, w2l + (size_t)i * 4096, b2,
                                       dxD, NVV);
    // ---- GCN branch ----
    mfma_lin<<<GBG, 256, 0, stream>>>(gxA, 64, nullptr, 0, nullptr, 0,
                                      wg1h + (size_t)i * 4096, wg1l + (size_t)i * 4096,
                                      nullptr, nullptr, xw, NGG, 64, 0);
    gcn_conv_k<<<NGG, 64, 0, stream>>>(xw, srcv, eidx, offs, dinv, bG1, hg, 1);
    mfma_lin<<<GBG, 256, 0, stream>>>(hg, 64, nullptr, 0, nullptr, 0,
                                      wg2h + (size_t)i * 4096, wg2l + (size_t)i * 4096,
                                      nullptr, nullptr, xw, NGG, 64, 0);
    gcn_conv_k<<<NGG, 64, 0, stream>>>(xw, srcv, eidx, offs, dinv, bG2, gxD, 0);
    // ---- cross-domain ----
    t64_k<<<GBG, 256, 0, stream>>>(gxD, 64, 0, NGG, nullptr, btGh, btGl, 3008);
    hipMemsetAsync(god, 0, (size_t)NVV * 64 * 4, stream);
    mfma_big<0><<<dim3(GBV, 6), 256, 0, stream>>>(rbf, NGG, btGh, btGl, 3008,
                                                  god, NVV, NGG, 512);
    if (i < 3) {
      t64_k<<<GBV, 256, 0, stream>>>(dxD, 64, 0, NVV, nullptr, btDh, btDl, 6016);
      hipMemsetAsync(dog, 0, (size_t)NGG * 64 * 4, stream);
      mfma_big<0><<<dim3(GBG, 12), 256, 0, stream>>>(rbfT, NVV, btDh, btDl, 6016,
                                                     dog, NGG, NVV, 512);
    }
    float* dxOut = (i == 3) ? (float*)d_out : dxA;
    mfma_lin<<<GBV, 256, 0, stream>>>(dxD, 64, god, 64, nullptr, 0,
                                      wmh + (size_t)i * 8192, wml + (size_t)i * 8192,
                                      bm, nullptr, dxOut, NVV, 128, 0);
    if (i < 3)
      mfma_lin<<<GBG, 256, 0, stream>>>(dog, 64, gxD, 64, nullptr, 0,
                                        wmh + (size_t)i * 8192, wml + (size_t)i * 8192,
                                        bm, nullptr, gxA, NGG, 128, 0);
  }
}